// Round 6
// baseline (446.571 us; speedup 1.0000x reference)
//
#include <hip/hip_runtime.h>
#include <stdint.h>

using s16x8 = __attribute__((ext_vector_type(8))) short;
using f32x4 = __attribute__((ext_vector_type(4))) float;

#define HW 1024
#define INC 256
#define EMB 512
#define NPX 32768

#define OFF_CS 0
#define OFF_CN 8388608
#define OFF_D  16777216
#define OFF_DN 25165824
#define OFF_PO 50331648

__device__ __forceinline__ uint32_t f2bf(float f) {
  uint32_t u = __float_as_uint(f);
  return (u + 0x7FFFu + ((u >> 16) & 1u)) >> 16;
}
// XOR swizzle for K1's LDS tiles
__device__ __forceinline__ int lswz(int row, int byte) {
  return byte ^ (((row >> 2) & 7) << 4);
}

// ---------------- K0: normalized rep matrix R[1024][512] bf16 ---------------------
__global__ __launch_bounds__(64) void k_prep(
    const float* __restrict__ rep_w, const float* __restrict__ rep_b,
    const float* __restrict__ neg_w, const float* __restrict__ neg_b,
    uint16_t* __restrict__ R) {
  int rb = blockIdx.x, lane = threadIdx.x;       // rb = class*4 + mode
  int c = rb >> 2, md = rb & 3;
  const float* w  = (md == 0) ? rep_w : neg_w;
  const float* bb = (md == 0) ? rep_b : neg_b;
  int base = (md == 0) ? c * EMB : (c * 3 + md - 1) * EMB;
  float v[8]; float ss = 0.f;
#pragma unroll
  for (int j = 0; j < 8; ++j) {
    float t = w[base + lane * 8 + j] + bb[base + lane * 8 + j];
    v[j] = t; ss += t * t;
  }
#pragma unroll
  for (int o = 1; o < 64; o <<= 1) ss += __shfl_xor(ss, o, 64);
  float inv = 1.f / fmaxf(sqrtf(ss), 1e-12f);
  uint16_t* dst = R + rb * EMB + lane * 8;
#pragma unroll
  for (int j = 0; j < 8; ++j) dst[j] = (uint16_t)f2bf(v[j] * inv);
}

// ---------------- K1: emb = x * W_emb^T  (M=px, N=e, K=c), bf16 out + norm partials
__global__ __launch_bounds__(256) void k_gemm1(
    const float* __restrict__ x, const float* __restrict__ wemb,
    uint16_t* __restrict__ emb, float* __restrict__ nparts) {
  int bid = blockIdx.x;
  int w = (bid & 7) * 128 + (bid >> 3);          // XCD swizzle (1024 = 8*128)
  int e_tile = w & 3, px_tile = w >> 2;
  int e0 = e_tile * 128, px0 = px_tile * 128;
  int bimg = px0 >> 10, hw0 = px0 & 1023;
  int tid = threadIdx.x, lane = tid & 63, wid = tid >> 6;
  int wm = wid >> 1, wn = wid & 1, lr = lane & 15, lk = lane >> 4;
  __shared__ __align__(16) char smA[16384];      // [128 px][64 c] bf16, swizzled
  __shared__ __align__(16) char smB[16384];      // [128 e ][64 c] bf16, swizzled
  f32x4 acc[4][4] = {};
  const float4* x4 = (const float4*)x;
  const float4* w4 = (const float4*)wemb;
  for (int kt = 0; kt < INC; kt += 64) {
    if (kt) __syncthreads();
    // stage A: x rows (c) -> LDS [px][c] bf16 (transpose + convert in regs)
#pragma unroll
    for (int i = 0; i < 4; ++i) {
      int p = tid + i * 256;
      int c2 = p >> 5, px4 = p & 31;             // c-pair index, px float4-chunk
      int gi = ((bimg * INC + kt + c2 * 2) * HW + hw0) >> 2;
      float4 fa = x4[gi + px4];
      float4 fb = x4[gi + 256 + px4];
      float fa_[4] = {fa.x, fa.y, fa.z, fa.w};
      float fb_[4] = {fb.x, fb.y, fb.z, fb.w};
#pragma unroll
      for (int j = 0; j < 4; ++j) {
        int px = px4 * 4 + j;
        uint32_t val = f2bf(fa_[j]) | (f2bf(fb_[j]) << 16);
        *(uint32_t*)(smA + px * 128 + lswz(px, c2 * 4)) = val;
      }
    }
    // stage B: W_emb [e][c] -> LDS bf16 (layout-preserving)
#pragma unroll
    for (int i = 0; i < 8; ++i) {
      int q = tid + i * 256;
      int er = q >> 4, c4 = q & 15;
      float4 f = w4[(((e0 + er) * INC + kt) >> 2) + c4];
      uint2 val;
      val.x = f2bf(f.x) | (f2bf(f.y) << 16);
      val.y = f2bf(f.z) | (f2bf(f.w) << 16);
      *(uint2*)(smB + er * 128 + lswz(er, c4 * 8)) = val;
    }
    __syncthreads();
#pragma unroll
    for (int kk = 0; kk < 64; kk += 32) {
      s16x8 a[4], b[4];
#pragma unroll
      for (int mi = 0; mi < 4; ++mi) {
        int row = wm * 64 + mi * 16 + lr;
        a[mi] = *(const s16x8*)(smA + row * 128 + lswz(row, (kk + lk * 8) * 2));
      }
#pragma unroll
      for (int ni = 0; ni < 4; ++ni) {
        int row = wn * 64 + ni * 16 + lr;
        b[ni] = *(const s16x8*)(smB + row * 128 + lswz(row, (kk + lk * 8) * 2));
      }
#pragma unroll
      for (int mi = 0; mi < 4; ++mi)
#pragma unroll
        for (int ni = 0; ni < 4; ++ni)
          acc[mi][ni] = __builtin_amdgcn_mfma_f32_16x16x32_bf16(a[mi], b[ni], acc[mi][ni], 0, 0, 0);
    }
  }
  // epilogue: emb bf16 (lane-pair packed u32 stores) + norm partials (NO atomics)
#pragma unroll
  for (int mi = 0; mi < 4; ++mi) {
#pragma unroll
    for (int r = 0; r < 4; ++r) {
      int pxg = px0 + wm * 64 + mi * 16 + lk * 4 + r;
      float ss = 0.f;
#pragma unroll
      for (int ni = 0; ni < 4; ++ni) {
        float v = acc[mi][ni][r];
        ss += v * v;
        uint32_t bf = f2bf(v);
        uint32_t other = (uint32_t)__shfl_xor((int)bf, 1, 64);
        if (!(lane & 1)) {
          int e = e0 + wn * 64 + ni * 16 + lr;
          *(uint32_t*)(emb + pxg * EMB + e) = bf | (other << 16);
        }
      }
      ss += __shfl_xor(ss, 1, 64);
      ss += __shfl_xor(ss, 2, 64);
      ss += __shfl_xor(ss, 4, 64);
      ss += __shfl_xor(ss, 8, 64);
      if (lr == 0) nparts[(e_tile * 2 + wn) * NPX + pxg] = ss;
    }
  }
}

// ---------------- K2: dots = R * emb^T, LDS-FREE (direct fragment loads from L2) --
__global__ __launch_bounds__(256) void k_gemm2(
    const uint16_t* __restrict__ Rm, const uint16_t* __restrict__ emb,
    const float* __restrict__ nparts, float* __restrict__ out,
    float* __restrict__ psum_part) {
  int bid = blockIdx.x;
  int w = (bid & 7) * 256 + (bid >> 3);          // XCD swizzle (2048 = 8*256)
  int px_tile = w >> 3, rep_tile = w & 7;        // 8 rep-blocks of one px-tile land
  int px0 = px_tile * 128, r0 = rep_tile * 128;  // consecutive -> same XCD L2
  int bimg = px0 >> 10;
  int tid = threadIdx.x, lane = tid & 63, wid = tid >> 6;
  int wm = wid >> 1, wn = wid & 1, lr = lane & 15, lk = lane >> 4;
  __shared__ __align__(16) char ep_s[4 * 1184];  // epilogue transpose scratch only
  f32x4 acc[4][4] = {};
  // per-lane fragment base addrs: row stride 1024 B (512 bf16), k-chunk = lk*16 B
  const char* Ab = (const char*)Rm  + (r0  + wm * 64 + lr) * 1024 + lk * 16;
  const char* Bb = (const char*)emb + (px0 + wn * 64 + lr) * 1024 + lk * 16;
  // K-loop: 16 steps of k=32; no LDS, no barriers — pure register dataflow
#pragma unroll
  for (int ks = 0; ks < 16; ++ks) {
    s16x8 a[4], b[4];
#pragma unroll
    for (int mi = 0; mi < 4; ++mi)
      a[mi] = *(const s16x8*)(Ab + mi * 16384 + ks * 64);
#pragma unroll
    for (int ni = 0; ni < 4; ++ni)
      b[ni] = *(const s16x8*)(Bb + ni * 16384 + ks * 64);
#pragma unroll
    for (int mi = 0; mi < 4; ++mi)
#pragma unroll
      for (int ni = 0; ni < 4; ++ni)
        acc[mi][ni] = __builtin_amdgcn_mfma_f32_16x16x32_bf16(a[mi], b[ni], acc[mi][ni], 0, 0, 0);
  }
  // fused epilogue with per-wave LDS-bounce transpose (same-wave, no barriers)
  char* ep = ep_s + wid * 1184;
  int hwbase = (px0 & 1023) + wn * 64;
  int obase = (bimg * 256) * HW + hwbase;
  float invn[4], psacc[4];
#pragma unroll
  for (int ni = 0; ni < 4; ++ni) {
    int px = px0 + wn * 64 + ni * 16 + lr;
    float s = 0.f;
#pragma unroll
    for (int t = 0; t < 8; ++t) s += nparts[t * NPX + px];
    invn[ni] = rsqrtf(fmaxf(s, 1e-24f));
    psacc[ni] = 0.f;
  }
#pragma unroll
  for (int mi = 0; mi < 4; ++mi) {
    int clsl = wm * 16 + mi * 4 + lk;            // class within block [0,32)
    int cls = (r0 >> 2) + clsl;                  // global class
    float pl[7][4];                              // [plane][ni], static indices
#pragma unroll
    for (int ni = 0; ni < 4; ++ni) {
      float in = invn[ni];
      float d0 = acc[mi][ni][0] * in;
      float d1 = acc[mi][ni][1] * in;
      float d2 = acc[mi][ni][2] * in;
      float d3 = acc[mi][ni][3] * in;
      float q0 = fmaxf(2.f - 2.f * d0, 0.f);     // dist^2
      float q1 = fmaxf(2.f - 2.f * d1, 0.f);
      float q2 = fmaxf(2.f - 2.f * d2, 0.f);
      float q3 = fmaxf(2.f - 2.f * d3, 0.f);
      float dist0 = sqrtf(q0);
      float qmin = fminf(q1, fminf(q2, q3));
      float negmin = sqrtf(qmin);
      float pen = 0.3f * fmaxf(2.f - negmin, 0.f);
      float tt = dist0 + pen;
      float probs = __expf(-2.f * tt * tt);      // inv2s2 = 2
      pl[0][ni] = probs;                         // cls_score (unnormalized)
      pl[1][ni] = __expf(-2.f * qmin);           // cls_score_neg
      pl[2][ni] = dist0;                         // distances
      pl[3][ni] = sqrtf(q1);                     // distances_neg m=0
      pl[4][ni] = sqrtf(q2);                     // m=1
      pl[5][ni] = sqrtf(q3);                     // m=2
      pl[6][ni] = __expf(-2.f * q0);             // probs_ori
      psacc[ni] += probs;
    }
    int bc = obase + cls * HW;
    int bn = OFF_DN + (bimg * 768 + cls * 3) * HW + hwbase;
    int pbase[7] = { OFF_CS + bc, OFF_CN + bc, OFF_D + bc,
                     bn, bn + HW, bn + 2 * HW, OFF_PO + bc };
#pragma unroll
    for (int p = 0; p < 7; ++p) {
#pragma unroll
      for (int ni = 0; ni < 4; ++ni)
        *(float*)(ep + lk * 288 + (ni * 16 + lr) * 4) = pl[p][ni];
      float4 v = *(const float4*)(ep + lk * 288 + lr * 16);   // same-wave LDS bounce
      *(float4*)(&out[pbase[p] + 4 * lr]) = v;                // 256B-contig segments
    }
  }
#pragma unroll
  for (int ni = 0; ni < 4; ++ni) {
    float s = psacc[ni];
    s += __shfl_xor(s, 16, 64);
    s += __shfl_xor(s, 32, 64);
    if (lk == 0)
      psum_part[(rep_tile * 2 + wm) * NPX + px0 + wn * 64 + ni * 16 + lr] = s;
  }
}

// ---------------- K2b: inv_psum[px] = 1 / sum_t psum_part[t][px] ------------------
__global__ __launch_bounds__(256) void k_psum(const float* __restrict__ psum_part,
                                              float* __restrict__ inv_ps) {
  int px = blockIdx.x * 256 + threadIdx.x;       // 128 blocks
  float s = 0.f;
#pragma unroll
  for (int t = 0; t < 16; ++t) s += psum_part[t * NPX + px];
  inv_ps[px] = 1.f / s;
}

// ---------------- K3: cls_score *= inv_psum (pure stream) -------------------------
__global__ __launch_bounds__(256) void k_norm(float* __restrict__ out,
                                              const float* __restrict__ inv_ps) {
  int idx4 = blockIdx.x * 256 + threadIdx.x;     // one float4 each, 8192 blocks
  int base = idx4 << 2;
  int b = base >> 18, hw = base & 1023;
  float4 p = *(const float4*)&inv_ps[(b << 10) | hw];
  float4* o4 = (float4*)out;
  float4 v = o4[idx4];
  v.x *= p.x; v.y *= p.y; v.z *= p.z; v.w *= p.w;
  o4[idx4] = v;
}

extern "C" void kernel_launch(void* const* d_in, const int* in_sizes, int n_in,
                              void* d_out, int out_size, void* d_ws, size_t ws_size,
                              hipStream_t stream) {
  (void)in_sizes; (void)n_in; (void)out_size; (void)ws_size;
  const float* x     = (const float*)d_in[0];
  const float* wemb  = (const float*)d_in[1];
  const float* rep_w = (const float*)d_in[2];
  const float* rep_b = (const float*)d_in[3];
  const float* neg_w = (const float*)d_in[4];
  const float* neg_b = (const float*)d_in[5];
  float* out = (float*)d_out;
  char* ws = (char*)d_ws;
  uint16_t* R         = (uint16_t*)ws;                      // 1 MB
  float*    nparts    = (float*)(ws + (1 << 20));           // 8  x 32768 x 4 = 1 MB
  float*    psum_part = (float*)(ws + (2 << 20));           // 16 x 32768 x 4 = 2 MB
  float*    inv_ps    = (float*)(ws + (4 << 20));           // 128 KB
  uint16_t* emb       = (uint16_t*)(ws + (5 << 20));        // 33.5 MB
  hipLaunchKernelGGL(k_prep,  dim3(1024), dim3(64),  0, stream,
                     rep_w, rep_b, neg_w, neg_b, R);
  hipLaunchKernelGGL(k_gemm1, dim3(1024), dim3(256), 0, stream, x, wemb, emb, nparts);
  hipLaunchKernelGGL(k_gemm2, dim3(2048), dim3(256), 0, stream, R, emb, nparts, out, psum_part);
  hipLaunchKernelGGL(k_psum,  dim3(128),  dim3(256), 0, stream, psum_part, inv_ps);
  hipLaunchKernelGGL(k_norm,  dim3(8192), dim3(256), 0, stream, out, inv_ps);
}

// Round 8
// 389.890 us; speedup vs baseline: 1.1454x; 1.1454x over previous
//
#include <hip/hip_runtime.h>
#include <stdint.h>

using s16x8 = __attribute__((ext_vector_type(8))) short;
using f32x4 = __attribute__((ext_vector_type(4))) float;

#define HW 1024
#define INC 256
#define EMB 512

#define OFF_CS 0
#define OFF_CN 8388608
#define OFF_D  16777216
#define OFF_DN 25165824
#define OFF_PO 50331648

__device__ __forceinline__ uint32_t f2bf(float f) {
  uint32_t u = __float_as_uint(f);
  return (u + 0x7FFFu + ((u >> 16) & 1u)) >> 16;
}
// phase-1 tile swizzle (K1-proven): XOR byte bits 4-6 with row bits 2-4
__device__ __forceinline__ int lswz(int row, int byte) {
  return byte ^ (((row >> 2) & 7) << 4);
}

// ---------------- K0: normalized rep matrix R[1024][512] bf16 ---------------------
__global__ __launch_bounds__(64) void k_prep(
    const float* __restrict__ rep_w, const float* __restrict__ rep_b,
    const float* __restrict__ neg_w, const float* __restrict__ neg_b,
    uint16_t* __restrict__ R) {
  int rb = blockIdx.x, lane = threadIdx.x;       // rb = class*4 + mode
  int c = rb >> 2, md = rb & 3;
  const float* w  = (md == 0) ? rep_w : neg_w;
  const float* bb = (md == 0) ? rep_b : neg_b;
  int base = (md == 0) ? c * EMB : (c * 3 + md - 1) * EMB;
  float v[8]; float ss = 0.f;
#pragma unroll
  for (int j = 0; j < 8; ++j) {
    float t = w[base + lane * 8 + j] + bb[base + lane * 8 + j];
    v[j] = t; ss += t * t;
  }
#pragma unroll
  for (int o = 1; o < 64; o <<= 1) ss += __shfl_xor(ss, o, 64);
  float inv = 1.f / fmaxf(sqrtf(ss), 1e-12f);
  uint16_t* dst = R + rb * EMB + lane * 8;
#pragma unroll
  for (int j = 0; j < 8; ++j) dst[j] = (uint16_t)f2bf(v[j] * inv);
}

// ---------------- K1+K2 fused: per 128-px tile, emb in LDS, all 1024 reps ---------
// LDS map (byte offsets in L[155648]):
//   embS [0,131072)      128px x 1024B rows (512 bf16), swizzle byte^((px&7)<<4)
//   smA  [73728,90112)   phase1 x-tile  (overlaps embS rows 72.. : safe by ordering)
//   smB  [90112,155648)  phase1 W-tile  (dead before embS rows written / Rbuf used)
//   Rbuf [131072,147456) phase2 R chunk 128rep x 128B, swizzle byte^((row&7)<<4)
//   nrm  [147456,149504) [4][128] f32 norm partials
//   psl  [131072,132096) [2][128] f32 (reuses Rbuf after final barrier)
__global__ __launch_bounds__(512, 2) void k_fused(
    const float* __restrict__ x, const float* __restrict__ wemb,
    const uint16_t* __restrict__ Rm, float* __restrict__ out,
    float* __restrict__ inv_ps) {
  __shared__ __align__(16) char L[155648];
  char* embS = L;
  char* smA  = L + 73728;
  char* smB  = L + 90112;
  char* Rbuf = L + 131072;
  float* nrm = (float*)(L + 147456);
  float* psl = (float*)(L + 131072);

  int bx = blockIdx.x;
  int px0 = bx * 128, bimg = bx >> 3, hw0 = px0 & 1023;
  int tid = threadIdx.x, lane = tid & 63, wid = tid >> 6;
  int lr = lane & 15, lk = lane >> 4;

  // prefetch phase-2 R chunk 0 early (hides cold R fetch under phase 1)
  int rrow = tid >> 2, rsl = tid & 3;
  const char* Rb = (const char*)Rm;
  uint4 rs0 = *(const uint4*)(Rb + rrow * 1024 + rsl * 16);
  uint4 rs1 = *(const uint4*)(Rb + rrow * 1024 + rsl * 16 + 64);

  // ---- phase 1: emb(128px, 512e) = x_tile(128px,256c) @ Wemb^T ----
  int wm1 = wid >> 2, wn1 = wid & 3;             // wave tile: 64px x 128e
  f32x4 acc1[4][8] = {};
  const float4* x4 = (const float4*)x;
  const float4* w4 = (const float4*)wemb;
  for (int ck = 0; ck < INC; ck += 64) {
    if (ck) __syncthreads();
    // stage x: [128px][64c] bf16 (transpose+convert in regs)
#pragma unroll
    for (int i = 0; i < 2; ++i) {
      int p = tid + i * 512;
      int c2 = p >> 5, px4 = p & 31;
      int gi = ((bimg * INC + ck + c2 * 2) * HW + hw0) >> 2;
      float4 fa = x4[gi + px4];
      float4 fb = x4[gi + 256 + px4];
      float fa_[4] = {fa.x, fa.y, fa.z, fa.w};
      float fb_[4] = {fb.x, fb.y, fb.z, fb.w};
#pragma unroll
      for (int j = 0; j < 4; ++j) {
        int px = px4 * 4 + j;
        uint32_t val = f2bf(fa_[j]) | (f2bf(fb_[j]) << 16);
        *(uint32_t*)(smA + px * 128 + lswz(px, c2 * 4)) = val;
      }
    }
    // stage Wemb: [512e][64c] bf16 (layout-preserving)
#pragma unroll
    for (int i = 0; i < 16; ++i) {
      int q = tid + i * 512;
      int er = q >> 4, c4 = q & 15;
      float4 f = w4[er * 64 + (ck >> 2) + c4];
      uint2 val;
      val.x = f2bf(f.x) | (f2bf(f.y) << 16);
      val.y = f2bf(f.z) | (f2bf(f.w) << 16);
      *(uint2*)(smB + er * 128 + lswz(er, c4 * 8)) = val;
    }
    __syncthreads();
#pragma unroll
    for (int kk = 0; kk < 64; kk += 32) {
      s16x8 a[4], b[8];
#pragma unroll
      for (int mi = 0; mi < 4; ++mi) {
        int row = wm1 * 64 + mi * 16 + lr;
        a[mi] = *(const s16x8*)(smA + row * 128 + lswz(row, (kk + lk * 8) * 2));
      }
#pragma unroll
      for (int ni = 0; ni < 8; ++ni) {
        int row = wn1 * 128 + ni * 16 + lr;
        b[ni] = *(const s16x8*)(smB + row * 128 + lswz(row, (kk + lk * 8) * 2));
      }
#pragma unroll
      for (int mi = 0; mi < 4; ++mi)
#pragma unroll
        for (int ni = 0; ni < 8; ++ni)
          acc1[mi][ni] = __builtin_amdgcn_mfma_f32_16x16x32_bf16(a[mi], b[ni], acc1[mi][ni], 0, 0, 0);
    }
  }
  __syncthreads();                               // staging reads done; smA/smB dead
  // phase-1 epilogue: emb -> embS (swizzled, packed u32) + norm partials -> nrm
#pragma unroll
  for (int mi = 0; mi < 4; ++mi) {
#pragma unroll
    for (int r = 0; r < 4; ++r) {
      int px = wm1 * 64 + mi * 16 + lk * 4 + r;
      float ss = 0.f;
#pragma unroll
      for (int ni = 0; ni < 8; ++ni) {
        float v = acc1[mi][ni][r];
        ss += v * v;
        uint32_t bf = f2bf(v);
        uint32_t other = (uint32_t)__shfl_xor((int)bf, 1, 64);
        if (!(lane & 1)) {
          int ebyte = wn1 * 256 + ni * 32 + lr * 2;
          *(uint32_t*)(embS + px * 1024 + (ebyte ^ ((px & 7) << 4))) = bf | (other << 16);
        }
      }
      ss += __shfl_xor(ss, 1, 64);
      ss += __shfl_xor(ss, 2, 64);
      ss += __shfl_xor(ss, 4, 64);
      ss += __shfl_xor(ss, 8, 64);
      if (lr == 0) nrm[wn1 * 128 + px] = ss;
    }
  }
  __syncthreads();

  // ---- phase 2: dots = R(1024,512) @ emb^T, 8 chunks of 128 reps ----
  int wm2 = wid >> 2, wn2 = wid & 3;             // wave tile: 64rep x 32px
  float invn2[2];
#pragma unroll
  for (int bi = 0; bi < 2; ++bi) {
    int px = wn2 * 32 + bi * 16 + lr;
    float s = nrm[px] + nrm[128 + px] + nrm[256 + px] + nrm[384 + px];
    invn2[bi] = rsqrtf(fmaxf(s, 1e-24f));
  }
  f32x4 acc2[4][2] = {};
  float ps0 = 0.f, ps1 = 0.f;
  int hwb = hw0 + wn2 * 32;
  for (int c = 0; c < 64; ++c) {                 // c = rc*8 + kt (k chunks of 64)
    __syncthreads();                             // prior chunk reads done
    int wb = rrow * 128, wsz = (rrow & 7) << 4;
    *(uint4*)(Rbuf + wb + ((rsl * 16) ^ wsz)) = rs0;
    *(uint4*)(Rbuf + wb + ((rsl * 16 + 64) ^ wsz)) = rs1;
    __syncthreads();
    if (c < 63) {                                // T14: issue next chunk's loads now
      int cn = c + 1;
      const char* src = Rb + ((cn >> 3) * 128 + rrow) * 1024 + (cn & 7) * 128 + rsl * 16;
      rs0 = *(const uint4*)(src);
      rs1 = *(const uint4*)(src + 64);
    }
    int kt = c & 7;
#pragma unroll
    for (int ks = 0; ks < 2; ++ks) {
      s16x8 a[4], b[2];
#pragma unroll
      for (int ai = 0; ai < 4; ++ai) {
        int row = wm2 * 64 + ai * 16 + lr;
        a[ai] = *(const s16x8*)(Rbuf + row * 128 + ((ks * 64 + lk * 16) ^ ((row & 7) << 4)));
      }
#pragma unroll
      for (int bi = 0; bi < 2; ++bi) {
        int px = wn2 * 32 + bi * 16 + lr;
        b[bi] = *(const s16x8*)(embS + px * 1024 + ((kt * 128 + ks * 64 + lk * 16) ^ ((px & 7) << 4)));
      }
#pragma unroll
      for (int ai = 0; ai < 4; ++ai)
#pragma unroll
        for (int bi = 0; bi < 2; ++bi)
          acc2[ai][bi] = __builtin_amdgcn_mfma_f32_16x16x32_bf16(a[ai], b[bi], acc2[ai][bi], 0, 0, 0);
    }
    if (kt == 7) {                               // rep-chunk done: fused epilogue
      int rc = c >> 3;
#pragma unroll
      for (int ai = 0; ai < 4; ++ai) {
        int cls = rc * 32 + wm2 * 16 + ai * 4 + lk;
        int bc = ((bimg << 8) + cls) << 10;
        int bn = OFF_DN + ((bimg * 768 + cls * 3) << 10);
#pragma unroll
        for (int bi = 0; bi < 2; ++bi) {
          float in = invn2[bi];
          int hw = hwb + bi * 16 + lr;
          float d0 = acc2[ai][bi][0] * in;
          float d1 = acc2[ai][bi][1] * in;
          float d2 = acc2[ai][bi][2] * in;
          float d3 = acc2[ai][bi][3] * in;
          float q0 = fmaxf(2.f - 2.f * d0, 0.f);
          float q1 = fmaxf(2.f - 2.f * d1, 0.f);
          float q2 = fmaxf(2.f - 2.f * d2, 0.f);
          float q3 = fmaxf(2.f - 2.f * d3, 0.f);
          float dist0 = sqrtf(q0);
          float qmin = fminf(q1, fminf(q2, q3));
          float negmin = sqrtf(qmin);
          float pen = 0.3f * fmaxf(2.f - negmin, 0.f);
          float tt = dist0 + pen;
          float probs = __expf(-2.f * tt * tt);  // inv2s2 = 2
          out[OFF_CS + bc + hw] = probs;
          out[OFF_CN + bc + hw] = __expf(-2.f * qmin);
          out[OFF_D  + bc + hw] = dist0;
          out[OFF_PO + bc + hw] = __expf(-2.f * q0);
          out[bn + hw]        = sqrtf(q1);
          out[bn + 1024 + hw] = sqrtf(q2);
          out[bn + 2048 + hw] = sqrtf(q3);
          if (bi == 0) ps0 += probs; else ps1 += probs;
          acc2[ai][bi] = (f32x4){0.f, 0.f, 0.f, 0.f};
        }
      }
    }
  }
  // block saw ALL classes: finish cls_score normalizer here (no extra kernel)
  ps0 += __shfl_xor(ps0, 16, 64); ps0 += __shfl_xor(ps0, 32, 64);
  ps1 += __shfl_xor(ps1, 16, 64); ps1 += __shfl_xor(ps1, 32, 64);
  __syncthreads();                               // last chunk reads done; Rbuf free
  if (lk == 0) {
    psl[wm2 * 128 + wn2 * 32 + lr] = ps0;
    psl[wm2 * 128 + wn2 * 32 + 16 + lr] = ps1;
  }
  __syncthreads();
  if (tid < 128) {
    float s = psl[tid] + psl[128 + tid];
    inv_ps[px0 + tid] = 1.f / s;
  }
}

// ---------------- K3: cls_score *= inv_psum (pure stream) -------------------------
__global__ __launch_bounds__(256) void k_norm(float* __restrict__ out,
                                              const float* __restrict__ inv_ps) {
  int idx4 = blockIdx.x * 256 + threadIdx.x;     // one float4 each, 8192 blocks
  int base = idx4 << 2;
  int b = base >> 18, hw = base & 1023;
  float4 p = *(const float4*)&inv_ps[(b << 10) | hw];
  float4* o4 = (float4*)out;
  float4 v = o4[idx4];
  v.x *= p.x; v.y *= p.y; v.z *= p.z; v.w *= p.w;
  o4[idx4] = v;
}

extern "C" void kernel_launch(void* const* d_in, const int* in_sizes, int n_in,
                              void* d_out, int out_size, void* d_ws, size_t ws_size,
                              hipStream_t stream) {
  (void)in_sizes; (void)n_in; (void)out_size; (void)ws_size;
  const float* x     = (const float*)d_in[0];
  const float* wemb  = (const float*)d_in[1];
  const float* rep_w = (const float*)d_in[2];
  const float* rep_b = (const float*)d_in[3];
  const float* neg_w = (const float*)d_in[4];
  const float* neg_b = (const float*)d_in[5];
  float* out = (float*)d_out;
  char* ws = (char*)d_ws;
  uint16_t* R      = (uint16_t*)ws;              // 1 MB
  float*    inv_ps = (float*)(ws + (1 << 20));   // 128 KB
  hipLaunchKernelGGL(k_prep,  dim3(1024), dim3(64),  0, stream,
                     rep_w, rep_b, neg_w, neg_b, R);
  hipLaunchKernelGGL(k_fused, dim3(256),  dim3(512), 0, stream, x, wemb, R, out, inv_ps);
  hipLaunchKernelGGL(k_norm,  dim3(8192), dim3(256), 0, stream, out, inv_ps);
}